// Round 3
// baseline (807.345 us; speedup 1.0000x reference)
//
#include <hip/hip_runtime.h>
#include <hip/hip_bf16.h>

#define B_    8
#define DIM_  256
#define NH_   8
#define HD_   32
#define KD_   16
#define HOUT_ 512
#define N_    1024
#define SCALE_ 0.25f
#define EPS_  1e-3f

typedef unsigned short u16;

__device__ __forceinline__ float b2f(u16 u) {
    union { unsigned int i; float f; } c;
    c.i = ((unsigned int)u) << 16;
    return c.f;
}

__device__ __forceinline__ u16 f2b(float f) {
    union { float f; unsigned int i; } c;
    c.f = f;
    unsigned int x = c.i;
    return (u16)((x + 0x7fffu + ((x >> 16) & 1u)) >> 16);  // RNE
}

// ---------------- Kernel 1: qkv = BN(qkv_w @ x) -> ws bf16 ----------------
// grid = B*HOUT (4096), block = 256, each thread computes 4 consecutive n.
__global__ __launch_bounds__(256) void k_qkv(
    const float* __restrict__ x, const float* __restrict__ w,
    const float* __restrict__ g, const float* __restrict__ bb,
    const float* __restrict__ mm, const float* __restrict__ vv,
    u16* __restrict__ qkv)
{
    __shared__ float w_s[DIM_];
    int blk = blockIdx.x;
    int b = blk >> 9, o = blk & 511;
    int t = threadIdx.x;
    w_s[t] = w[o * DIM_ + t];
    __syncthreads();
    const float* xb = x + b * DIM_ * N_;
    float a0 = 0.f, a1 = 0.f, a2 = 0.f, a3 = 0.f;
    #pragma unroll 4
    for (int c = 0; c < DIM_; ++c) {
        float wv = w_s[c];
        float4 u = ((const float4*)(xb + c * N_))[t];
        a0 += wv * u.x;
        a1 += wv * u.y;
        a2 += wv * u.z;
        a3 += wv * u.w;
    }
    float inv  = g[o] / sqrtf(vv[o] + EPS_);
    float beta = bb[o] - mm[o] * inv;
    ushort4 r;
    r.x = f2b(a0 * inv + beta);
    r.y = f2b(a1 * inv + beta);
    r.z = f2b(a2 * inv + beta);
    r.w = f2b(a3 * inv + beta);
    ((ushort4*)(qkv + (b * HOUT_ + o) * N_))[t] = r;
}

// ---------------- Kernel 2: full attention per (b,h,qchunk) ----------------
// Each block owns 256 queries, walks all 1024 keys in 4 LDS stages.
// Softmax without max-subtraction (|s| small by data scale); s clamped to
// +/-80 so exp stays finite and l > 0 always.
// grid = B*NH*4 = 256, block = 256 (one query per thread).
__global__ __launch_bounds__(256) void k_attn(
    const u16* __restrict__ qkv, float* __restrict__ xattn)
{
    __shared__ float k_s[256][17];
    __shared__ float v_s[256][33];
    int blk = blockIdx.x;
    int qc = blk & 3;
    int h  = (blk >> 2) & 7;
    int b  = blk >> 5;
    int t  = threadIdx.x;
    const u16* base = qkv + (b * HOUT_ + h * 64) * N_;  // q: d, k: 16+d, v: 32+d
    int i = qc * 256 + t;

    float q[16];
    #pragma unroll
    for (int d = 0; d < 16; ++d) q[d] = b2f(base[d * N_ + i]) * SCALE_;

    float acc[32];
    #pragma unroll
    for (int d = 0; d < 32; ++d) acc[d] = 0.f;
    float l = 0.f;

    for (int sub = 0; sub < 4; ++sub) {
        int j0 = sub * 256;
        __syncthreads();
        #pragma unroll
        for (int d = 0; d < 16; ++d) k_s[t][d] = b2f(base[(16 + d) * N_ + j0 + t]);
        #pragma unroll
        for (int d = 0; d < 32; ++d) v_s[t][d] = b2f(base[(32 + d) * N_ + j0 + t]);
        __syncthreads();
        #pragma unroll 2
        for (int j = 0; j < 256; ++j) {
            float s0 = 0.f, s1 = 0.f;
            #pragma unroll
            for (int d = 0; d < 8; ++d) {
                s0 += q[d] * k_s[j][d];
                s1 += q[8 + d] * k_s[j][8 + d];
            }
            float s = fminf(fmaxf(s0 + s1, -80.f), 80.f);
            float p = __expf(s);
            l += p;
            #pragma unroll
            for (int d = 0; d < 32; ++d) acc[d] += p * v_s[j][d];
        }
    }
    float invl = 1.f / fmaxf(l, 1e-30f);
    // xattn channel c = h*32 + d  (HD=32 per head)
    float* op = xattn + (b * DIM_ + h * HD_) * N_ + i;
    #pragma unroll
    for (int d = 0; d < 32; ++d) op[d * N_] = acc[d] * invl;
}

// ------- Kernel 3: xattn += BN(depthwise 3x3 conv on v) -------
// grid = B*DIM*N/256 = 8192, block = 256, one element per thread.
__global__ __launch_bounds__(256) void k_pe(
    const u16* __restrict__ qkv, const float* __restrict__ pw,
    const float* __restrict__ g, const float* __restrict__ bb,
    const float* __restrict__ mm, const float* __restrict__ vv,
    float* __restrict__ xattn)
{
    int idx = blockIdx.x * 256 + threadIdx.x;  // = (b*256 + c)*1024 + n
    int n = idx & 1023;
    int c = (idx >> 10) & 255;
    int b = idx >> 18;
    int h = c >> 5, d = c & 31;

    const u16* vrow = qkv + (b * HOUT_ + h * 64 + 32 + d) * N_;
    int y = n >> 5, x0 = n & 31;
    float s = 0.f;
    #pragma unroll
    for (int dy = -1; dy <= 1; ++dy) {
        int yy = y + dy;
        if (yy < 0 || yy > 31) continue;
        #pragma unroll
        for (int dx = -1; dx <= 1; ++dx) {
            int xx = x0 + dx;
            if (xx < 0 || xx > 31) continue;
            s += pw[c * 9 + (dy + 1) * 3 + (dx + 1)] * b2f(vrow[yy * 32 + xx]);
        }
    }
    float inv = g[c] / sqrtf(vv[c] + EPS_);
    xattn[idx] += s * inv + (bb[c] - mm[c] * inv);
}

// ---------------- Kernel 4: out = BN(proj_w @ x_attn) -> fp32 ----------------
// grid = B*DIM (2048), block = 256, 4 n per thread.
__global__ __launch_bounds__(256) void k_proj(
    const float* __restrict__ xattn, const float* __restrict__ w,
    const float* __restrict__ g, const float* __restrict__ bb,
    const float* __restrict__ mm, const float* __restrict__ vv,
    float* __restrict__ out)
{
    __shared__ float w_s[DIM_];
    int blk = blockIdx.x;
    int b = blk >> 8, o = blk & 255;
    int t = threadIdx.x;
    w_s[t] = w[o * DIM_ + t];
    __syncthreads();
    const float* xb = xattn + b * DIM_ * N_;
    float a0 = 0.f, a1 = 0.f, a2 = 0.f, a3 = 0.f;
    #pragma unroll 4
    for (int c = 0; c < DIM_; ++c) {
        float wv = w_s[c];
        float4 u = ((const float4*)(xb + c * N_))[t];
        a0 += wv * u.x;
        a1 += wv * u.y;
        a2 += wv * u.z;
        a3 += wv * u.w;
    }
    float inv  = g[o] / sqrtf(vv[o] + EPS_);
    float beta = bb[o] - mm[o] * inv;
    float4 r;
    r.x = a0 * inv + beta;
    r.y = a1 * inv + beta;
    r.z = a2 * inv + beta;
    r.w = a3 * inv + beta;
    ((float4*)(out + (b * DIM_ + o) * N_))[t] = r;
}

extern "C" void kernel_launch(void* const* d_in, const int* in_sizes, int n_in,
                              void* d_out, int out_size, void* d_ws, size_t ws_size,
                              hipStream_t stream)
{
    const float* x      = (const float*)d_in[0];
    const float* qkv_w  = (const float*)d_in[1];
    const float* qkv_g  = (const float*)d_in[2];
    const float* qkv_b  = (const float*)d_in[3];
    const float* qkv_m  = (const float*)d_in[4];
    const float* qkv_v  = (const float*)d_in[5];
    const float* pe_w   = (const float*)d_in[6];
    const float* pe_g   = (const float*)d_in[7];
    const float* pe_b   = (const float*)d_in[8];
    const float* pe_m   = (const float*)d_in[9];
    const float* pe_v   = (const float*)d_in[10];
    const float* proj_w = (const float*)d_in[11];
    const float* proj_g = (const float*)d_in[12];
    const float* proj_b = (const float*)d_in[13];
    const float* proj_m = (const float*)d_in[14];
    const float* proj_v = (const float*)d_in[15];
    float* out = (float*)d_out;

    // Workspace: qkv bf16 (8 MB) + xattn fp32 (8 MB) = 16 MB total.
    u16*   qkv   = (u16*)d_ws;                            // 8*512*1024 bf16 = 8 MB
    float* xattn = (float*)((char*)d_ws + (size_t)B_ * HOUT_ * N_ * sizeof(u16));
                                                          // 8*256*1024 f32  = 8 MB

    hipLaunchKernelGGL(k_qkv, dim3(B_ * HOUT_), dim3(256), 0, stream,
                       x, qkv_w, qkv_g, qkv_b, qkv_m, qkv_v, qkv);
    hipLaunchKernelGGL(k_attn, dim3(B_ * NH_ * 4), dim3(256), 0, stream,
                       qkv, xattn);
    hipLaunchKernelGGL(k_pe, dim3(B_ * DIM_ * N_ / 256), dim3(256), 0, stream,
                       qkv, pe_w, pe_g, pe_b, pe_m, pe_v, xattn);
    hipLaunchKernelGGL(k_proj, dim3(B_ * DIM_), dim3(256), 0, stream,
                       xattn, proj_w, proj_g, proj_b, proj_m, proj_v, out);
}

// Round 4
// 211.547 us; speedup vs baseline: 3.8164x; 3.8164x over previous
//
#include <hip/hip_runtime.h>
#include <hip/hip_bf16.h>

#define B_    8
#define DIM_  256
#define NH_   8
#define HD_   32
#define KD_   16
#define HOUT_ 512
#define N_    1024
#define SCALE_ 0.25f
#define EPS_  1e-3f

typedef unsigned short u16;
typedef __attribute__((ext_vector_type(8))) short short8;   // 8 bf16 = 4 VGPR
typedef __attribute__((ext_vector_type(4))) float f32x4;    // MFMA acc

__device__ __forceinline__ float b2f(u16 u) {
    union { unsigned int i; float f; } c;
    c.i = ((unsigned int)u) << 16;
    return c.f;
}

__device__ __forceinline__ u16 f2b(float f) {
    union { float f; unsigned int i; } c;
    c.f = f;
    unsigned int x = c.i;
    return (u16)((x + 0x7fffu + ((x >> 16) & 1u)) >> 16);  // RNE
}

// ============ Kernel 1: qkv = BN(qkv_w @ x) -> ws bf16 ============
// Tiled GEMM: block tile 64o x 128n, thread tile 8o x 4n.
// grid = B * (512/64) * (1024/128) = 512, block = 256.
__global__ __launch_bounds__(256) void k_qkv(
    const float* __restrict__ x, const float* __restrict__ w,
    const float* __restrict__ g, const float* __restrict__ bb,
    const float* __restrict__ mm, const float* __restrict__ vv,
    u16* __restrict__ qkv)
{
    __shared__ float x_s[32][128];   // 16 KB
    __shared__ float w_t[32][68];    // [c][o] transposed, +4 pad, 8.7 KB
    int blk = blockIdx.x;
    int nb = blk & 7;
    int ob = (blk >> 3) & 7;
    int b  = blk >> 6;
    int t  = threadIdx.x;
    int tn = t & 31, to = t >> 5;

    float acc[8][4];
    #pragma unroll
    for (int i = 0; i < 8; ++i)
        acc[i][0] = acc[i][1] = acc[i][2] = acc[i][3] = 0.f;

    const float* xb = x + (size_t)b * DIM_ * N_ + nb * 128;
    const float* wb = w + (size_t)ob * 64 * DIM_;

    for (int c0 = 0; c0 < DIM_; c0 += 32) {
        __syncthreads();
        {   // stage x tile 32c x 128n (coalesced both sides)
            int c = t >> 3, n16 = (t & 7) * 16;
            const float4* src = (const float4*)(xb + (size_t)(c0 + c) * N_ + n16);
            float4* dst = (float4*)&x_s[c][n16];
            dst[0] = src[0]; dst[1] = src[1]; dst[2] = src[2]; dst[3] = src[3];
        }
        {   // stage w transposed: w_t[c][o]
            int o = t >> 2, c8 = (t & 3) * 8;
            const float* src = wb + o * DIM_ + c0 + c8;
            #pragma unroll
            for (int i = 0; i < 8; ++i) w_t[c8 + i][o] = src[i];
        }
        __syncthreads();
        #pragma unroll 8
        for (int cc = 0; cc < 32; ++cc) {
            float4 xv  = *(const float4*)&x_s[cc][tn * 4];
            float4 wa  = *(const float4*)&w_t[cc][to * 8];
            float4 wb4 = *(const float4*)&w_t[cc][to * 8 + 4];
            #define FMA4(o, s) acc[o][0] += (s)*xv.x; acc[o][1] += (s)*xv.y; \
                               acc[o][2] += (s)*xv.z; acc[o][3] += (s)*xv.w;
            FMA4(0, wa.x)  FMA4(1, wa.y)  FMA4(2, wa.z)  FMA4(3, wa.w)
            FMA4(4, wb4.x) FMA4(5, wb4.y) FMA4(6, wb4.z) FMA4(7, wb4.w)
            #undef FMA4
        }
    }
    #pragma unroll
    for (int oo = 0; oo < 8; ++oo) {
        int o = ob * 64 + to * 8 + oo;
        float inv  = g[o] / sqrtf(vv[o] + EPS_);
        float beta = bb[o] - mm[o] * inv;
        ushort4 r;
        r.x = f2b(acc[oo][0] * inv + beta);
        r.y = f2b(acc[oo][1] * inv + beta);
        r.z = f2b(acc[oo][2] * inv + beta);
        r.w = f2b(acc[oo][3] * inv + beta);
        *(ushort4*)(qkv + (size_t)(b * HOUT_ + o) * N_ + nb * 128 + tn * 4) = r;
    }
}

// ============ Kernel 2: MFMA flash attention ============
// grid = B*NH*16 = 1024 blocks, 256 thr = 4 waves. Block: 64 queries (16/wave),
// iterates 16 key-tiles of 64. QK^T: K=16 padded to 32 (quads 2,3 zero frags).
// Verified gfx950 layouts: A/B frag [m|n]=lane&15, k=quad*8+j; C/D col=lane&15,
// row=quad*4+reg. P transits LDS (bf16); V read direct as dwordx4 (keys are
// contiguous in qkv buffer). No max-subtraction; s clamped at 80.
__global__ __launch_bounds__(256) void k_attn(
    const u16* __restrict__ qkv, float* __restrict__ xattn)
{
    __shared__ u16   q_t[64][16];      // [q_local][d], pre-scaled, 2 KB
    __shared__ u16   k_t[64][16];      // [key_local][d] per tile, 2 KB
    __shared__ u16   p_s[4][16][72];   // per-wave P [q16][64 keys +8 pad], 9 KB
    __shared__ float o_s[4][32][17];   // per-wave O^T [d_v][q16 +1 pad], 8.5 KB

    int blk = blockIdx.x;
    int qb = blk & 15;
    int h  = (blk >> 4) & 7;
    int b  = blk >> 7;
    int t    = threadIdx.x;
    int wv_  = t >> 6;       // wave id 0..3
    int lane = t & 63;
    int quad = lane >> 4;
    int l16  = lane & 15;
    const u16* base = qkv + (size_t)(b * HOUT_ + h * 64) * N_;  // q:d, k:16+d, v:32+d

    {   // stage q transposed + scaled (x0.25 exact in bf16)
        int d = t >> 4, q4 = (t & 15) * 4;
        const u16* src = base + d * N_ + qb * 64 + q4;
        #pragma unroll
        for (int i = 0; i < 4; ++i) q_t[q4 + i][d] = f2b(b2f(src[i]) * SCALE_);
    }
    __syncthreads();

    short8 qf = {0, 0, 0, 0, 0, 0, 0, 0};
    if (quad < 2) qf = *(const short8*)&q_t[wv_ * 16 + l16][quad * 8];

    f32x4 oa0 = {0.f, 0.f, 0.f, 0.f};
    f32x4 oa1 = {0.f, 0.f, 0.f, 0.f};
    float l_acc[4] = {0.f, 0.f, 0.f, 0.f};

    for (int kt = 0; kt < 16; ++kt) {
        int key0 = kt * 64;
        __syncthreads();
        {   // stage k-tile transposed: k_t[key][d]
            int d = t >> 4, k4 = (t & 15) * 4;
            const u16* src = base + (16 + d) * N_ + key0 + k4;
            #pragma unroll
            for (int i = 0; i < 4; ++i) k_t[k4 + i][d] = src[i];
        }
        __syncthreads();

        // S = Q K^T (4 n-tiles of 16 keys), then P = exp(S) -> p_s + row sums
        #pragma unroll
        for (int nt = 0; nt < 4; ++nt) {
            short8 kf = {0, 0, 0, 0, 0, 0, 0, 0};
            if (quad < 2) kf = *(const short8*)&k_t[nt * 16 + l16][quad * 8];
            f32x4 zero = {0.f, 0.f, 0.f, 0.f};
            f32x4 s = __builtin_amdgcn_mfma_f32_16x16x32_bf16(qf, kf, zero, 0, 0, 0);
            #pragma unroll
            for (int r = 0; r < 4; ++r) {
                float p = __expf(fminf(s[r], 80.f));
                l_acc[r] += p;
                p_s[wv_][quad * 4 + r][nt * 16 + l16] = f2b(p);
            }
        }

        // O += P V  (2 K-chunks of 32 keys x 2 d_v tiles of 16)
        #pragma unroll
        for (int kc = 0; kc < 2; ++kc) {
            short8 pf = *(const short8*)&p_s[wv_][l16][kc * 32 + quad * 8];
            {
                const u16* vsrc = base + (size_t)(32 + l16) * N_ + key0 + kc * 32 + quad * 8;
                short8 vf = *(const short8*)vsrc;
                oa0 = __builtin_amdgcn_mfma_f32_16x16x32_bf16(pf, vf, oa0, 0, 0, 0);
            }
            {
                const u16* vsrc = base + (size_t)(48 + l16) * N_ + key0 + kc * 32 + quad * 8;
                short8 vf = *(const short8*)vsrc;
                oa1 = __builtin_amdgcn_mfma_f32_16x16x32_bf16(pf, vf, oa1, 0, 0, 0);
            }
        }
    }

    // full row-sums: reduce l over the 16 lanes of the low nibble
    #pragma unroll
    for (int r = 0; r < 4; ++r) {
        float v = l_acc[r];
        v += __shfl_xor(v, 1);
        v += __shfl_xor(v, 2);
        v += __shfl_xor(v, 4);
        v += __shfl_xor(v, 8);
        l_acc[r] = v;
    }
    // normalize + transpose O through LDS (C-layout -> [d_v][q])
    #pragma unroll
    for (int r = 0; r < 4; ++r) {
        o_s[wv_][l16][quad * 4 + r]      = oa0[r] / l_acc[r];
        o_s[wv_][16 + l16][quad * 4 + r] = oa1[r] / l_acc[r];
    }
    {   // coalesced write-out: 2 lanes cover one 64B channel-row segment
        int d = lane >> 1, qo = (lane & 1) * 8;
        float* dst = xattn + (size_t)(b * DIM_ + h * HD_ + d) * N_ + qb * 64 + wv_ * 16 + qo;
        #pragma unroll
        for (int i = 0; i < 8; ++i) dst[i] = o_s[wv_][d][qo + i];
    }
}

// ============ Kernel 3: xattn += BN(depthwise 3x3 conv on v) ============
__global__ __launch_bounds__(256) void k_pe(
    const u16* __restrict__ qkv, const float* __restrict__ pw,
    const float* __restrict__ g, const float* __restrict__ bb,
    const float* __restrict__ mm, const float* __restrict__ vv,
    float* __restrict__ xattn)
{
    int idx = blockIdx.x * 256 + threadIdx.x;
    int n = idx & 1023;
    int c = (idx >> 10) & 255;
    int b = idx >> 18;
    int h = c >> 5, d = c & 31;

    const u16* vrow = qkv + (size_t)(b * HOUT_ + h * 64 + 32 + d) * N_;
    int y = n >> 5, x0 = n & 31;
    float s = 0.f;
    #pragma unroll
    for (int dy = -1; dy <= 1; ++dy) {
        int yy = y + dy;
        if (yy < 0 || yy > 31) continue;
        #pragma unroll
        for (int dx = -1; dx <= 1; ++dx) {
            int xx = x0 + dx;
            if (xx < 0 || xx > 31) continue;
            s += pw[c * 9 + (dy + 1) * 3 + (dx + 1)] * b2f(vrow[yy * 32 + xx]);
        }
    }
    float inv = g[c] / sqrtf(vv[c] + EPS_);
    xattn[idx] += s * inv + (bb[c] - mm[c] * inv);
}

// ============ Kernel 4: out = BN(proj_w @ xattn) fp32 ============
// Block tile 32o x 128n, thread tile 4o x 4n, grid = 8*8*8 = 512.
__global__ __launch_bounds__(256) void k_proj(
    const float* __restrict__ xattn, const float* __restrict__ w,
    const float* __restrict__ g, const float* __restrict__ bb,
    const float* __restrict__ mm, const float* __restrict__ vv,
    float* __restrict__ out)
{
    __shared__ float x_s[32][128];
    __shared__ float w_t[32][36];
    int blk = blockIdx.x;
    int nb = blk & 7;
    int ob = (blk >> 3) & 7;
    int b  = blk >> 6;
    int t  = threadIdx.x;
    int tn = t & 31, to = t >> 5;

    float acc[4][4];
    #pragma unroll
    for (int i = 0; i < 4; ++i)
        acc[i][0] = acc[i][1] = acc[i][2] = acc[i][3] = 0.f;

    const float* xb = xattn + (size_t)b * DIM_ * N_ + nb * 128;
    const float* wb = w + (size_t)ob * 32 * DIM_;

    for (int c0 = 0; c0 < DIM_; c0 += 32) {
        __syncthreads();
        {
            int c = t >> 3, n16 = (t & 7) * 16;
            const float4* src = (const float4*)(xb + (size_t)(c0 + c) * N_ + n16);
            float4* dst = (float4*)&x_s[c][n16];
            dst[0] = src[0]; dst[1] = src[1]; dst[2] = src[2]; dst[3] = src[3];
        }
        {
            int o = t >> 3, c4 = (t & 7) * 4;
            const float* src = wb + o * DIM_ + c0 + c4;
            #pragma unroll
            for (int i = 0; i < 4; ++i) w_t[c4 + i][o] = src[i];
        }
        __syncthreads();
        #pragma unroll 8
        for (int cc = 0; cc < 32; ++cc) {
            float4 xv = *(const float4*)&x_s[cc][tn * 4];
            float4 wa = *(const float4*)&w_t[cc][to * 4];
            #define FMA4(o, s) acc[o][0] += (s)*xv.x; acc[o][1] += (s)*xv.y; \
                               acc[o][2] += (s)*xv.z; acc[o][3] += (s)*xv.w;
            FMA4(0, wa.x) FMA4(1, wa.y) FMA4(2, wa.z) FMA4(3, wa.w)
            #undef FMA4
        }
    }
    #pragma unroll
    for (int oo = 0; oo < 4; ++oo) {
        int o = ob * 32 + to * 4 + oo;
        float inv  = g[o] / sqrtf(vv[o] + EPS_);
        float beta = bb[o] - mm[o] * inv;
        float4 r;
        r.x = acc[oo][0] * inv + beta;
        r.y = acc[oo][1] * inv + beta;
        r.z = acc[oo][2] * inv + beta;
        r.w = acc[oo][3] * inv + beta;
        *(float4*)(out + (size_t)(b * DIM_ + o) * N_ + nb * 128 + tn * 4) = r;
    }
}

extern "C" void kernel_launch(void* const* d_in, const int* in_sizes, int n_in,
                              void* d_out, int out_size, void* d_ws, size_t ws_size,
                              hipStream_t stream)
{
    const float* x      = (const float*)d_in[0];
    const float* qkv_w  = (const float*)d_in[1];
    const float* qkv_g  = (const float*)d_in[2];
    const float* qkv_b  = (const float*)d_in[3];
    const float* qkv_m  = (const float*)d_in[4];
    const float* qkv_v  = (const float*)d_in[5];
    const float* pe_w   = (const float*)d_in[6];
    const float* pe_g   = (const float*)d_in[7];
    const float* pe_b   = (const float*)d_in[8];
    const float* pe_m   = (const float*)d_in[9];
    const float* pe_v   = (const float*)d_in[10];
    const float* proj_w = (const float*)d_in[11];
    const float* proj_g = (const float*)d_in[12];
    const float* proj_b = (const float*)d_in[13];
    const float* proj_m = (const float*)d_in[14];
    const float* proj_v = (const float*)d_in[15];
    float* out = (float*)d_out;

    // ws: qkv bf16 (8 MB) + xattn fp32 (8 MB)
    u16*   qkv   = (u16*)d_ws;
    float* xattn = (float*)((char*)d_ws + (size_t)B_ * HOUT_ * N_ * sizeof(u16));

    hipLaunchKernelGGL(k_qkv, dim3(512), dim3(256), 0, stream,
                       x, qkv_w, qkv_g, qkv_b, qkv_m, qkv_v, qkv);
    hipLaunchKernelGGL(k_attn, dim3(B_ * NH_ * 16), dim3(256), 0, stream,
                       qkv, xattn);
    hipLaunchKernelGGL(k_pe, dim3(B_ * DIM_ * N_ / 256), dim3(256), 0, stream,
                       qkv, pe_w, pe_g, pe_b, pe_m, pe_v, xattn);
    hipLaunchKernelGGL(k_proj, dim3(512), dim3(256), 0, stream,
                       xattn, proj_w, proj_g, proj_b, proj_m, proj_v, out);
}

// Round 5
// 169.941 us; speedup vs baseline: 4.7507x; 1.2448x over previous
//
#include <hip/hip_runtime.h>
#include <hip/hip_bf16.h>

#define B_    8
#define DIM_  256
#define NH_   8
#define HD_   32
#define KD_   16
#define HOUT_ 512
#define N_    1024
#define SCALE_ 0.25f
#define EPS_  1e-3f

typedef unsigned short u16;
typedef __attribute__((ext_vector_type(8))) short short8;   // 8 bf16 = 4 VGPR
typedef __attribute__((ext_vector_type(4))) float f32x4;    // MFMA acc

union Frag { short8 v; u16 e[8]; };
union H4   { uint2 u; u16 e[4]; };

__device__ __forceinline__ float b2f(u16 u) {
    union { unsigned int i; float f; } c;
    c.i = ((unsigned int)u) << 16;
    return c.f;
}

__device__ __forceinline__ u16 f2b(float f) {
    union { float f; unsigned int i; } c;
    c.f = f;
    unsigned int x = c.i;
    return (u16)((x + 0x7fffu + ((x >> 16) & 1u)) >> 16);  // RNE
}

// ============ Kernel 0: prep — weights fp32->bf16, fold BN ============
// grid = 512 x 256 (covers 131072 qkv_w elems; proj_w/bn in the low range)
__global__ __launch_bounds__(256) void k_prep(
    const float* __restrict__ qw, const float* __restrict__ pw,
    const float* __restrict__ qg, const float* __restrict__ qb,
    const float* __restrict__ qm, const float* __restrict__ qv,
    const float* __restrict__ pg, const float* __restrict__ pb,
    const float* __restrict__ pm, const float* __restrict__ pv,
    u16* __restrict__ wq_bf, u16* __restrict__ wp_bf,
    float2* __restrict__ bnq, float2* __restrict__ bnp)
{
    int i = blockIdx.x * 256 + threadIdx.x;          // 0 .. 131071
    wq_bf[i] = f2b(qw[i]);
    if (i < 65536) wp_bf[i] = f2b(pw[i]);
    if (i < 512) {
        float inv = qg[i] / sqrtf(qv[i] + EPS_);
        bnq[i] = make_float2(inv, qb[i] - qm[i] * inv);
    } else if (i < 768) {
        int o = i - 512;
        float inv = pg[o] / sqrtf(pv[o] + EPS_);
        bnp[o] = make_float2(inv, pb[o] - pm[o] * inv);
    }
}

// ============ Kernel 1: qkv = BN(qkv_w @ x) -> bf16, MFMA ============
// No LDS: A-frags b128 from pre-converted bf16 W; B-frags assembled from x
// (8 coalesced dword loads + cvt per frag). Block 64o x 128n, 4 waves 2x2.
// grid = 8b x 8ob x 8nb = 512.
__global__ __launch_bounds__(256) void k_qkv(
    const float* __restrict__ x, const u16* __restrict__ wbf,
    const float2* __restrict__ bn, u16* __restrict__ qkv)
{
    int blk = blockIdx.x;
    int nb = blk & 7, ob = (blk >> 3) & 7, b = blk >> 6;
    int t = threadIdx.x;
    int wv_ = t >> 6, lane = t & 63, quad = lane >> 4, l16 = lane & 15;
    int o_base = ob * 64 + (wv_ & 1) * 32;
    int n_base = nb * 128 + (wv_ >> 1) * 64;

    f32x4 acc[2][4];
    #pragma unroll
    for (int ot = 0; ot < 2; ++ot)
        #pragma unroll
        for (int nt = 0; nt < 4; ++nt) acc[ot][nt] = (f32x4){0.f, 0.f, 0.f, 0.f};

    const float* xb = x + (size_t)b * DIM_ * N_;
    for (int c0 = 0; c0 < DIM_; c0 += 32) {
        short8 af[2];
        #pragma unroll
        for (int ot = 0; ot < 2; ++ot)
            af[ot] = *(const short8*)(wbf + (size_t)(o_base + ot * 16 + l16) * DIM_ + c0 + quad * 8);
        Frag bf[4];
        #pragma unroll
        for (int nt = 0; nt < 4; ++nt) {
            const float* xc = xb + (size_t)(c0 + quad * 8) * N_ + n_base + nt * 16 + l16;
            #pragma unroll
            for (int j = 0; j < 8; ++j) bf[nt].e[j] = f2b(xc[(size_t)j * N_]);
        }
        #pragma unroll
        for (int ot = 0; ot < 2; ++ot)
            #pragma unroll
            for (int nt = 0; nt < 4; ++nt)
                acc[ot][nt] = __builtin_amdgcn_mfma_f32_16x16x32_bf16(af[ot], bf[nt].v, acc[ot][nt], 0, 0, 0);
    }
    #pragma unroll
    for (int ot = 0; ot < 2; ++ot)
        #pragma unroll
        for (int r = 0; r < 4; ++r) {
            int o = o_base + ot * 16 + quad * 4 + r;
            float2 ib = bn[o];
            u16* dst = qkv + (size_t)(b * HOUT_ + o) * N_ + n_base + l16;
            #pragma unroll
            for (int nt = 0; nt < 4; ++nt)
                dst[nt * 16] = f2b(acc[ot][nt][r] * ib.x + ib.y);
        }
}

// ============ Kernel 2: MFMA flash attention, barrier-light ============
// grid = B*NH*16 = 1024 blocks, 4 waves, 64 q/block (16/wave). K staged in
// 4 chunks of 256 keys (9 barriers total). Rows padded: k_t/q_t 24 u16
// (48 B, 16B-aligned b128, <=2-way), p_s 80 u16 (quads on disjoint octets).
__global__ __launch_bounds__(256) void k_attn(
    const u16* __restrict__ qkv, float* __restrict__ xattn)
{
    __shared__ u16   q_t[64][24];      // [q][d] 3 KB
    __shared__ u16   k_t[256][24];     // [key][d] 12 KB
    __shared__ u16   p_s[4][16][80];   // per-wave P [q16][64keys] 10 KB
    __shared__ float o_s[4][32][17];   // per-wave O^T 8.5 KB

    int blk = blockIdx.x;
    int qb = blk & 15;
    int h  = (blk >> 4) & 7;
    int b  = blk >> 7;
    int t    = threadIdx.x;
    int wv_  = t >> 6;
    int lane = t & 63;
    int quad = lane >> 4;
    int l16  = lane & 15;
    const u16* base = qkv + (size_t)(b * HOUT_ + h * 64) * N_;  // q:d, k:16+d, v:32+d

    {   // stage q transposed+scaled: lane=q idiom (conflict-free writes)
        int q = t & 63, d4 = (t >> 6) * 4;
        H4 hh;
        #pragma unroll
        for (int i = 0; i < 4; ++i)
            hh.e[i] = f2b(b2f(base[(size_t)(d4 + i) * N_ + qb * 64 + q]) * SCALE_);
        *(uint2*)&q_t[q][d4] = hh.u;
    }
    __syncthreads();

    short8 qf = {0, 0, 0, 0, 0, 0, 0, 0};
    if (quad < 2) qf = *(const short8*)&q_t[wv_ * 16 + l16][quad * 8];

    f32x4 oa0 = {0.f, 0.f, 0.f, 0.f};
    f32x4 oa1 = {0.f, 0.f, 0.f, 0.f};
    float l_acc[4] = {0.f, 0.f, 0.f, 0.f};

    for (int ch = 0; ch < 4; ++ch) {
        int ch0 = ch * 256;
        __syncthreads();
        {   // stage 256 keys: lane=key idiom, b64-packed writes
            #pragma unroll
            for (int d4 = 0; d4 < 16; d4 += 4) {
                H4 hh;
                #pragma unroll
                for (int i = 0; i < 4; ++i)
                    hh.e[i] = base[(size_t)(16 + d4 + i) * N_ + ch0 + t];
                *(uint2*)&k_t[t][d4] = hh.u;
            }
        }
        __syncthreads();

        for (int kt = 0; kt < 4; ++kt) {
            int key0 = ch0 + kt * 64;
            // S = Q K^T over 4 tiles of 16 keys; P = exp(S) -> p_s + row sums
            #pragma unroll
            for (int nt = 0; nt < 4; ++nt) {
                short8 kf = {0, 0, 0, 0, 0, 0, 0, 0};
                if (quad < 2) kf = *(const short8*)&k_t[kt * 64 + nt * 16 + l16][quad * 8];
                f32x4 zero = {0.f, 0.f, 0.f, 0.f};
                f32x4 s = __builtin_amdgcn_mfma_f32_16x16x32_bf16(qf, kf, zero, 0, 0, 0);
                #pragma unroll
                for (int r = 0; r < 4; ++r) {
                    float p = __expf(fminf(s[r], 80.f));
                    l_acc[r] += p;
                    p_s[wv_][quad * 4 + r][nt * 16 + l16] = f2b(p);
                }
            }
            // O += P V
            #pragma unroll
            for (int kc = 0; kc < 2; ++kc) {
                short8 pf = *(const short8*)&p_s[wv_][l16][kc * 32 + quad * 8];
                {
                    const u16* vsrc = base + (size_t)(32 + l16) * N_ + key0 + kc * 32 + quad * 8;
                    short8 vf = *(const short8*)vsrc;
                    oa0 = __builtin_amdgcn_mfma_f32_16x16x32_bf16(pf, vf, oa0, 0, 0, 0);
                }
                {
                    const u16* vsrc = base + (size_t)(48 + l16) * N_ + key0 + kc * 32 + quad * 8;
                    short8 vf = *(const short8*)vsrc;
                    oa1 = __builtin_amdgcn_mfma_f32_16x16x32_bf16(pf, vf, oa1, 0, 0, 0);
                }
            }
        }
    }

    // row-sums across the 16 key-lanes
    #pragma unroll
    for (int r = 0; r < 4; ++r) {
        float v = l_acc[r];
        v += __shfl_xor(v, 1);
        v += __shfl_xor(v, 2);
        v += __shfl_xor(v, 4);
        v += __shfl_xor(v, 8);
        l_acc[r] = v;
    }
    // normalize + transpose O through per-wave LDS
    #pragma unroll
    for (int r = 0; r < 4; ++r) {
        o_s[wv_][l16][quad * 4 + r]      = oa0[r] / l_acc[r];
        o_s[wv_][16 + l16][quad * 4 + r] = oa1[r] / l_acc[r];
    }
    {   // vectorized write-out: 2 lanes per channel-row, float4 x2
        int d = lane >> 1, qo = (lane & 1) * 8;
        float* dst = xattn + (size_t)(b * DIM_ + h * HD_ + d) * N_ + qb * 64 + wv_ * 16 + qo;
        float4 r0, r1;
        r0.x = o_s[wv_][d][qo + 0]; r0.y = o_s[wv_][d][qo + 1];
        r0.z = o_s[wv_][d][qo + 2]; r0.w = o_s[wv_][d][qo + 3];
        r1.x = o_s[wv_][d][qo + 4]; r1.y = o_s[wv_][d][qo + 5];
        r1.z = o_s[wv_][d][qo + 6]; r1.w = o_s[wv_][d][qo + 7];
        ((float4*)dst)[0] = r0;
        ((float4*)dst)[1] = r1;
    }
}

// ============ Kernel 3: xattn += BN(depthwise 3x3 conv on v) ============
__global__ __launch_bounds__(256) void k_pe(
    const u16* __restrict__ qkv, const float* __restrict__ pw,
    const float* __restrict__ g, const float* __restrict__ bb,
    const float* __restrict__ mm, const float* __restrict__ vv,
    float* __restrict__ xattn)
{
    int idx = blockIdx.x * 256 + threadIdx.x;
    int n = idx & 1023;
    int c = (idx >> 10) & 255;
    int b = idx >> 18;
    int h = c >> 5, d = c & 31;

    const u16* vrow = qkv + (size_t)(b * HOUT_ + h * 64 + 32 + d) * N_;
    int y = n >> 5, x0 = n & 31;
    float s = 0.f;
    #pragma unroll
    for (int dy = -1; dy <= 1; ++dy) {
        int yy = y + dy;
        if (yy < 0 || yy > 31) continue;
        #pragma unroll
        for (int dx = -1; dx <= 1; ++dx) {
            int xx = x0 + dx;
            if (xx < 0 || xx > 31) continue;
            s += pw[c * 9 + (dy + 1) * 3 + (dx + 1)] * b2f(vrow[yy * 32 + xx]);
        }
    }
    float inv = g[c] / sqrtf(vv[c] + EPS_);
    xattn[idx] += s * inv + (bb[c] - mm[c] * inv);
}

// ============ Kernel 4: out = BN(proj_w @ xattn) fp32, MFMA ============
// Same structure as k_qkv; B-frags from fp32 xattn. grid = 8b x 4ob x 8nb = 256.
__global__ __launch_bounds__(256) void k_proj(
    const float* __restrict__ xattn, const u16* __restrict__ wbf,
    const float2* __restrict__ bn, float* __restrict__ out)
{
    int blk = blockIdx.x;
    int nb = blk & 7, ob = (blk >> 3) & 3, b = blk >> 5;
    int t = threadIdx.x;
    int wv_ = t >> 6, lane = t & 63, quad = lane >> 4, l16 = lane & 15;
    int o_base = ob * 64 + (wv_ & 1) * 32;
    int n_base = nb * 128 + (wv_ >> 1) * 64;

    f32x4 acc[2][4];
    #pragma unroll
    for (int ot = 0; ot < 2; ++ot)
        #pragma unroll
        for (int nt = 0; nt < 4; ++nt) acc[ot][nt] = (f32x4){0.f, 0.f, 0.f, 0.f};

    const float* xb = xattn + (size_t)b * DIM_ * N_;
    for (int c0 = 0; c0 < DIM_; c0 += 32) {
        short8 af[2];
        #pragma unroll
        for (int ot = 0; ot < 2; ++ot)
            af[ot] = *(const short8*)(wbf + (size_t)(o_base + ot * 16 + l16) * DIM_ + c0 + quad * 8);
        Frag bf[4];
        #pragma unroll
        for (int nt = 0; nt < 4; ++nt) {
            const float* xc = xb + (size_t)(c0 + quad * 8) * N_ + n_base + nt * 16 + l16;
            #pragma unroll
            for (int j = 0; j < 8; ++j) bf[nt].e[j] = f2b(xc[(size_t)j * N_]);
        }
        #pragma unroll
        for (int ot = 0; ot < 2; ++ot)
            #pragma unroll
            for (int nt = 0; nt < 4; ++nt)
                acc[ot][nt] = __builtin_amdgcn_mfma_f32_16x16x32_bf16(af[ot], bf[nt].v, acc[ot][nt], 0, 0, 0);
    }
    #pragma unroll
    for (int ot = 0; ot < 2; ++ot)
        #pragma unroll
        for (int r = 0; r < 4; ++r) {
            int o = o_base + ot * 16 + quad * 4 + r;
            float2 ib = bn[o];
            float* dst = out + (size_t)(b * DIM_ + o) * N_ + n_base + l16;
            #pragma unroll
            for (int nt = 0; nt < 4; ++nt)
                dst[nt * 16] = acc[ot][nt][r] * ib.x + ib.y;
        }
}

extern "C" void kernel_launch(void* const* d_in, const int* in_sizes, int n_in,
                              void* d_out, int out_size, void* d_ws, size_t ws_size,
                              hipStream_t stream)
{
    const float* x      = (const float*)d_in[0];
    const float* qkv_w  = (const float*)d_in[1];
    const float* qkv_g  = (const float*)d_in[2];
    const float* qkv_b  = (const float*)d_in[3];
    const float* qkv_m  = (const float*)d_in[4];
    const float* qkv_v  = (const float*)d_in[5];
    const float* pe_w   = (const float*)d_in[6];
    const float* pe_g   = (const float*)d_in[7];
    const float* pe_b   = (const float*)d_in[8];
    const float* pe_m   = (const float*)d_in[9];
    const float* pe_v   = (const float*)d_in[10];
    const float* proj_w = (const float*)d_in[11];
    const float* proj_g = (const float*)d_in[12];
    const float* proj_b = (const float*)d_in[13];
    const float* proj_m = (const float*)d_in[14];
    const float* proj_v = (const float*)d_in[15];
    float* out = (float*)d_out;

    // ws layout
    char* p = (char*)d_ws;
    u16*    qkv   = (u16*)p;          p += (size_t)B_ * HOUT_ * N_ * sizeof(u16);   // 8 MB
    float*  xattn = (float*)p;        p += (size_t)B_ * DIM_ * N_ * sizeof(float);  // 8 MB
    u16*    wq_bf = (u16*)p;          p += (size_t)HOUT_ * DIM_ * sizeof(u16);      // 256 KB
    u16*    wp_bf = (u16*)p;          p += (size_t)DIM_ * DIM_ * sizeof(u16);       // 128 KB
    float2* bnq   = (float2*)p;       p += 512 * sizeof(float2);                    // 4 KB
    float2* bnp   = (float2*)p;                                                     // 2 KB

    hipLaunchKernelGGL(k_prep, dim3(512), dim3(256), 0, stream,
                       qkv_w, proj_w, qkv_g, qkv_b, qkv_m, qkv_v,
                       proj_g, proj_b, proj_m, proj_v, wq_bf, wp_bf, bnq, bnp);
    hipLaunchKernelGGL(k_qkv, dim3(512), dim3(256), 0, stream,
                       x, wq_bf, bnq, qkv);
    hipLaunchKernelGGL(k_attn, dim3(B_ * NH_ * 16), dim3(256), 0, stream,
                       qkv, xattn);
    hipLaunchKernelGGL(k_pe, dim3(B_ * DIM_ * N_ / 256), dim3(256), 0, stream,
                       qkv, pe_w, pe_g, pe_b, pe_m, pe_v, xattn);
    hipLaunchKernelGGL(k_proj, dim3(256), dim3(256), 0, stream,
                       xattn, wp_bf, bnp, out);
}

// Round 7
// 159.543 us; speedup vs baseline: 5.0604x; 1.0652x over previous
//
#include <hip/hip_runtime.h>
#include <hip/hip_bf16.h>

#define B_    8
#define DIM_  256
#define NH_   8
#define HD_   32
#define KD_   16
#define HOUT_ 512
#define N_    1024
#define SCALE_ 0.25f
#define EPS_  1e-3f

typedef unsigned short u16;
typedef __attribute__((ext_vector_type(8))) short short8;   // 8 bf16 (4 VGPR)
typedef __attribute__((ext_vector_type(4))) float f32x4;

union H4 { uint2 u; u16 e[4]; };

__device__ __forceinline__ float b2f(u16 u) {
    union { unsigned int i; float f; } c;
    c.i = ((unsigned int)u) << 16;
    return c.f;
}

__device__ __forceinline__ u16 f2b(float f) {
    union { float f; unsigned int i; } c;
    c.f = f;
    unsigned int x = c.i;
    return (u16)((x + 0x7fffu + ((x >> 16) & 1u)) >> 16);  // RNE
}

// ============ Kernel 0: prep — weights->bf16, fold all BN ============
// grid = 512 x 256.
__global__ __launch_bounds__(256) void k_prep(
    const float* __restrict__ qw, const float* __restrict__ pw,
    const float* __restrict__ pew,
    const float* __restrict__ qg, const float* __restrict__ qb,
    const float* __restrict__ qm, const float* __restrict__ qv,
    const float* __restrict__ pg, const float* __restrict__ pb,
    const float* __restrict__ pm, const float* __restrict__ pv,
    const float* __restrict__ eg, const float* __restrict__ eb,
    const float* __restrict__ em, const float* __restrict__ ev,
    u16* __restrict__ wq_bf, u16* __restrict__ wp_bf,
    float2* __restrict__ bnq, float2* __restrict__ bnp,
    float* __restrict__ wpe, float* __restrict__ bnpe)
{
    int i = blockIdx.x * 256 + threadIdx.x;          // 0 .. 131071
    wq_bf[i] = f2b(qw[i]);
    if (i < 65536) wp_bf[i] = f2b(pw[i]);
    if (i < 512) {
        float inv = qg[i] / sqrtf(qv[i] + EPS_);
        bnq[i] = make_float2(inv, qb[i] - qm[i] * inv);
    } else if (i < 768) {
        int o = i - 512;
        float inv = pg[o] / sqrtf(pv[o] + EPS_);
        bnp[o] = make_float2(inv, pb[o] - pm[o] * inv);
    }
    if (i < 2304) {                    // pe: fold inv into the 9 taps
        int c = i / 9;
        float inv = eg[c] / sqrtf(ev[c] + EPS_);
        wpe[i] = pew[i] * inv;
        if (i % 9 == 0) bnpe[c] = eb[c] - em[c] * inv;
    }
}

// ============ Kernel 0b: xT[b][n][c] bf16 <- x[b][c][n] fp32 ============
// 64x64 LDS tile transpose; grid = 8b x 4ct x 16nt = 512.
__global__ __launch_bounds__(256) void k_xt(
    const float* __restrict__ x, u16* __restrict__ xT)
{
    __shared__ float t_s[64][65];
    int blk = blockIdx.x;
    int nt = blk & 15, ct = (blk >> 4) & 3, b = blk >> 6;
    int t = threadIdx.x;
    int c0 = ct * 64, n0 = nt * 64;
    #pragma unroll
    for (int i = 0; i < 16; ++i) {
        int idx = i * 256 + t;
        int c = idx >> 6, n = idx & 63;
        t_s[n][c] = x[(size_t)(b * DIM_ + c0 + c) * N_ + n0 + n];
    }
    __syncthreads();
    #pragma unroll
    for (int i = 0; i < 16; ++i) {
        int idx = i * 256 + t;
        int n = idx >> 6, c = idx & 63;
        xT[(size_t)(b * N_ + n0 + n) * DIM_ + c0 + c] = f2b(t_s[n][c]);
    }
}

// ============ Kernel 1: qkv = BN(qkv_w @ x) -> bf16 [o][n], MFMA ============
// A-frags b128 from bf16 W, B-frags b128 from xT. Block 64o x 128n, 4 waves.
// grid = 8b x 8ob x 8nb = 512.
__global__ __launch_bounds__(256) void k_qkv(
    const u16* __restrict__ xT, const u16* __restrict__ wbf,
    const float2* __restrict__ bn, u16* __restrict__ qkv)
{
    int blk = blockIdx.x;
    int nb = blk & 7, ob = (blk >> 3) & 7, b = blk >> 6;
    int t = threadIdx.x;
    int wv_ = t >> 6, lane = t & 63, quad = lane >> 4, l16 = lane & 15;
    int o_base = ob * 64 + (wv_ & 1) * 32;
    int n_base = nb * 128 + (wv_ >> 1) * 64;

    f32x4 acc[2][4];
    #pragma unroll
    for (int ot = 0; ot < 2; ++ot)
        #pragma unroll
        for (int nt = 0; nt < 4; ++nt) acc[ot][nt] = (f32x4){0.f, 0.f, 0.f, 0.f};

    const u16* xb = xT + (size_t)b * N_ * DIM_;
    for (int c0 = 0; c0 < DIM_; c0 += 32) {
        short8 af[2];
        #pragma unroll
        for (int ot = 0; ot < 2; ++ot)
            af[ot] = *(const short8*)(wbf + (size_t)(o_base + ot * 16 + l16) * DIM_ + c0 + quad * 8);
        short8 bf[4];
        #pragma unroll
        for (int nt = 0; nt < 4; ++nt)
            bf[nt] = *(const short8*)(xb + (size_t)(n_base + nt * 16 + l16) * DIM_ + c0 + quad * 8);
        #pragma unroll
        for (int ot = 0; ot < 2; ++ot)
            #pragma unroll
            for (int nt = 0; nt < 4; ++nt)
                acc[ot][nt] = __builtin_amdgcn_mfma_f32_16x16x32_bf16(af[ot], bf[nt], acc[ot][nt], 0, 0, 0);
    }
    #pragma unroll
    for (int ot = 0; ot < 2; ++ot)
        #pragma unroll
        for (int r = 0; r < 4; ++r) {
            int o = o_base + ot * 16 + quad * 4 + r;
            float2 ib = bn[o];
            u16* dst = qkv + (size_t)(b * HOUT_ + o) * N_ + n_base + l16;
            #pragma unroll
            for (int nt = 0; nt < 4; ++nt)
                dst[nt * 16] = f2b(acc[ot][nt][r] * ib.x + ib.y);
        }
}

// ============ Kernel 2: MFMA flash attention + fused pe conv ============
// grid = B*NH*16 = 1024 blocks, 4 waves, 64 q (=2 image rows) per block.
// QK^T: K=16 padded to 32 (quads 2,3 zero) — R5-verified form. After the key
// loop the block computes its head's depthwise-3x3 pe on its 2 rows (+halo)
// and adds it before the bf16 [n][c] transposed store. k_t/p_s LDS is
// aliased for the v-patch after the main loop.
struct MainSmem { u16 k_t[256][24]; u16 p_s[4][16][80]; };
union  SmemU    { MainSmem m; float v_pe[128][33]; };

__global__ __launch_bounds__(256) void k_attn(
    const u16* __restrict__ qkv, const float* __restrict__ wpe,
    const float* __restrict__ bnpe, u16* __restrict__ xattnT)
{
    __shared__ SmemU su;
    __shared__ u16   q_t[64][24];
    __shared__ float o_s[4][32][17];

    int blk = blockIdx.x;
    int qb = blk & 15;
    int h  = (blk >> 4) & 7;
    int b  = blk >> 7;
    int t    = threadIdx.x;
    int wv_  = t >> 6;
    int lane = t & 63;
    int quad = lane >> 4;
    int l16  = lane & 15;
    const u16* base = qkv + (size_t)(b * HOUT_ + h * 64) * N_;  // q:d, k:16+d, v:32+d

    {   // stage q transposed+scaled (lane = q, conflict-free)
        int q = t & 63, d4 = (t >> 6) * 4;
        H4 hh;
        #pragma unroll
        for (int i = 0; i < 4; ++i)
            hh.e[i] = f2b(b2f(base[(size_t)(d4 + i) * N_ + qb * 64 + q]) * SCALE_);
        *(uint2*)&q_t[q][d4] = hh.u;
    }
    __syncthreads();

    short8 qf = {0, 0, 0, 0, 0, 0, 0, 0};
    if (quad < 2) qf = *(const short8*)&q_t[wv_ * 16 + l16][quad * 8];

    f32x4 oa0 = {0.f, 0.f, 0.f, 0.f};
    f32x4 oa1 = {0.f, 0.f, 0.f, 0.f};
    float l_acc[4] = {0.f, 0.f, 0.f, 0.f};

    for (int ch = 0; ch < 4; ++ch) {
        int ch0 = ch * 256;
        __syncthreads();
        {   // stage 256 keys (lane = key, conflict-free)
            #pragma unroll
            for (int d4 = 0; d4 < 16; d4 += 4) {
                H4 hh;
                #pragma unroll
                for (int i = 0; i < 4; ++i)
                    hh.e[i] = base[(size_t)(16 + d4 + i) * N_ + ch0 + t];
                *(uint2*)&su.m.k_t[t][d4] = hh.u;
            }
        }
        __syncthreads();

        for (int kt = 0; kt < 4; ++kt) {
            int key0 = ch0 + kt * 64;
            #pragma unroll
            for (int nt = 0; nt < 4; ++nt) {
                short8 kf = {0, 0, 0, 0, 0, 0, 0, 0};
                if (quad < 2) kf = *(const short8*)&su.m.k_t[kt * 64 + nt * 16 + l16][quad * 8];
                f32x4 zero = {0.f, 0.f, 0.f, 0.f};
                f32x4 s = __builtin_amdgcn_mfma_f32_16x16x32_bf16(qf, kf, zero, 0, 0, 0);
                #pragma unroll
                for (int r = 0; r < 4; ++r) {
                    float p = __expf(fminf(s[r], 80.f));
                    l_acc[r] += p;
                    su.m.p_s[wv_][quad * 4 + r][nt * 16 + l16] = f2b(p);
                }
            }
            #pragma unroll
            for (int kc = 0; kc < 2; ++kc) {
                short8 pf = *(const short8*)&su.m.p_s[wv_][l16][kc * 32 + quad * 8];
                {
                    const u16* vsrc = base + (size_t)(32 + l16) * N_ + key0 + kc * 32 + quad * 8;
                    oa0 = __builtin_amdgcn_mfma_f32_16x16x32_bf16(pf, *(const short8*)vsrc, oa0, 0, 0, 0);
                }
                {
                    const u16* vsrc = base + (size_t)(48 + l16) * N_ + key0 + kc * 32 + quad * 8;
                    oa1 = __builtin_amdgcn_mfma_f32_16x16x32_bf16(pf, *(const short8*)vsrc, oa1, 0, 0, 0);
                }
            }
        }
    }

    // row-sums across the 16 key-lanes
    #pragma unroll
    for (int r = 0; r < 4; ++r) {
        float v = l_acc[r];
        v += __shfl_xor(v, 1);
        v += __shfl_xor(v, 2);
        v += __shfl_xor(v, 4);
        v += __shfl_xor(v, 8);
        l_acc[r] = v;
    }
    // normalized O -> per-wave LDS [d][q]
    #pragma unroll
    for (int r = 0; r < 4; ++r) {
        o_s[wv_][l16][quad * 4 + r]      = oa0[r] / l_acc[r];
        o_s[wv_][16 + l16][quad * 4 + r] = oa1[r] / l_acc[r];
    }
    __syncthreads();   // all waves done with k_t/p_s + o_s complete

    {   // stage v patch: rows 2qb-1 .. 2qb+2, 32 d channels, zeros off-image
        int ybase = qb * 2 - 1;
        #pragma unroll
        for (int i = 0; i < 16; ++i) {
            int idx = i * 256 + t;
            int d = idx >> 7, px = idx & 127;
            int y = ybase + (px >> 5);
            float v = 0.f;
            if (y >= 0 && y < 32)
                v = b2f(base[(size_t)(32 + d) * N_ + y * 32 + (px & 31)]);
            su.v_pe[px][d] = v;
        }
    }
    __syncthreads();

    {   // pe compute + add + transposed bf16 store
        int d = t & 31, pxg = t >> 5;        // 8 pixel-groups of 8
        int c = h * 32 + d;
        float w9[9];
        #pragma unroll
        for (int k = 0; k < 9; ++k) w9[k] = wpe[c * 9 + k];
        float beta = bnpe[c];
        #pragma unroll
        for (int ii = 0; ii < 8; ++ii) {
            int pl = pxg * 8 + ii;           // 0..63 local pixel
            int xx0 = pl & 31;
            float s = beta;
            #pragma unroll
            for (int dy = -1; dy <= 1; ++dy) {
                #pragma unroll
                for (int dx = -1; dx <= 1; ++dx) {
                    int xx = xx0 + dx;
                    if (xx < 0 || xx > 31) continue;
                    s += w9[(dy + 1) * 3 + (dx + 1)] * su.v_pe[pl + 32 + dy * 32 + dx][d];
                }
            }
            float o = o_s[pl >> 4][d][pl & 15];
            xattnT[(size_t)(b * N_ + qb * 64 + pl) * DIM_ + c] = f2b(o + s);
        }
    }
}

// ============ Kernel 4: out = BN(proj_w @ xattn) fp32, MFMA ============
// B-frags b128 direct from xattnT. grid = 8b x 4ob x 8nb = 256.
__global__ __launch_bounds__(256) void k_proj(
    const u16* __restrict__ xattnT, const u16* __restrict__ wbf,
    const float2* __restrict__ bn, float* __restrict__ out)
{
    int blk = blockIdx.x;
    int nb = blk & 7, ob = (blk >> 3) & 3, b = blk >> 5;
    int t = threadIdx.x;
    int wv_ = t >> 6, lane = t & 63, quad = lane >> 4, l16 = lane & 15;
    int o_base = ob * 64 + (wv_ & 1) * 32;
    int n_base = nb * 128 + (wv_ >> 1) * 64;

    f32x4 acc[2][4];
    #pragma unroll
    for (int ot = 0; ot < 2; ++ot)
        #pragma unroll
        for (int nt = 0; nt < 4; ++nt) acc[ot][nt] = (f32x4){0.f, 0.f, 0.f, 0.f};

    const u16* xb = xattnT + (size_t)b * N_ * DIM_;
    for (int c0 = 0; c0 < DIM_; c0 += 32) {
        short8 af[2];
        #pragma unroll
        for (int ot = 0; ot < 2; ++ot)
            af[ot] = *(const short8*)(wbf + (size_t)(o_base + ot * 16 + l16) * DIM_ + c0 + quad * 8);
        short8 bf[4];
        #pragma unroll
        for (int nt = 0; nt < 4; ++nt)
            bf[nt] = *(const short8*)(xb + (size_t)(n_base + nt * 16 + l16) * DIM_ + c0 + quad * 8);
        #pragma unroll
        for (int ot = 0; ot < 2; ++ot)
            #pragma unroll
            for (int nt = 0; nt < 4; ++nt)
                acc[ot][nt] = __builtin_amdgcn_mfma_f32_16x16x32_bf16(af[ot], bf[nt], acc[ot][nt], 0, 0, 0);
    }
    #pragma unroll
    for (int ot = 0; ot < 2; ++ot)
        #pragma unroll
        for (int r = 0; r < 4; ++r) {
            int o = o_base + ot * 16 + quad * 4 + r;
            float2 ib = bn[o];
            float* dst = out + (size_t)(b * DIM_ + o) * N_ + n_base + l16;
            #pragma unroll
            for (int nt = 0; nt < 4; ++nt)
                dst[nt * 16] = acc[ot][nt][r] * ib.x + ib.y;
        }
}

extern "C" void kernel_launch(void* const* d_in, const int* in_sizes, int n_in,
                              void* d_out, int out_size, void* d_ws, size_t ws_size,
                              hipStream_t stream)
{
    const float* x      = (const float*)d_in[0];
    const float* qkv_w  = (const float*)d_in[1];
    const float* qkv_g  = (const float*)d_in[2];
    const float* qkv_b  = (const float*)d_in[3];
    const float* qkv_m  = (const float*)d_in[4];
    const float* qkv_v  = (const float*)d_in[5];
    const float* pe_w   = (const float*)d_in[6];
    const float* pe_g   = (const float*)d_in[7];
    const float* pe_b   = (const float*)d_in[8];
    const float* pe_m   = (const float*)d_in[9];
    const float* pe_v   = (const float*)d_in[10];
    const float* proj_w = (const float*)d_in[11];
    const float* proj_g = (const float*)d_in[12];
    const float* proj_b = (const float*)d_in[13];
    const float* proj_m = (const float*)d_in[14];
    const float* proj_v = (const float*)d_in[15];
    float* out = (float*)d_out;

    // ws layout
    char* p = (char*)d_ws;
    u16*    qkv    = (u16*)p;    p += (size_t)B_ * HOUT_ * N_ * sizeof(u16);   // 8 MB
    u16*    xT     = (u16*)p;    p += (size_t)B_ * N_ * DIM_ * sizeof(u16);    // 4 MB
    u16*    xattnT = (u16*)p;    p += (size_t)B_ * N_ * DIM_ * sizeof(u16);    // 4 MB
    u16*    wq_bf  = (u16*)p;    p += (size_t)HOUT_ * DIM_ * sizeof(u16);      // 256 KB
    u16*    wp_bf  = (u16*)p;    p += (size_t)DIM_ * DIM_ * sizeof(u16);       // 128 KB
    float2* bnq    = (float2*)p; p += 512 * sizeof(float2);
    float2* bnp    = (float2*)p; p += 256 * sizeof(float2);
    float*  wpe    = (float*)p;  p += 2304 * sizeof(float);
    float*  bnpe   = (float*)p;

    hipLaunchKernelGGL(k_prep, dim3(512), dim3(256), 0, stream,
                       qkv_w, proj_w, pe_w,
                       qkv_g, qkv_b, qkv_m, qkv_v,
                       proj_g, proj_b, proj_m, proj_v,
                       pe_g, pe_b, pe_m, pe_v,
                       wq_bf, wp_bf, bnq, bnp, wpe, bnpe);
    hipLaunchKernelGGL(k_xt, dim3(512), dim3(256), 0, stream, x, xT);
    hipLaunchKernelGGL(k_qkv, dim3(512), dim3(256), 0, stream,
                       xT, wq_bf, bnq, qkv);
    hipLaunchKernelGGL(k_attn, dim3(B_ * NH_ * 16), dim3(256), 0, stream,
                       qkv, wpe, bnpe, xattnT);
    hipLaunchKernelGGL(k_proj, dim3(256), dim3(256), 0, stream,
                       xattnT, wp_bf, bnp, out);
}